// Round 9
// baseline (501.516 us; speedup 1.0000x reference)
//
#include <hip/hip_runtime.h>
#include <hip/hip_fp16.h>

// Message passing, gather formulation. e fp32 read once with NT loads;
// r compressed to fp16 (12.8MB, LLC-resident); atomic-free chunk-sorted CSR
// with u8 bases; NO global scan — segment starts allocated by wave-aggregated
// atomicAdd on one cursor (node order in pl is arbitrary; only per-node
// contiguity matters). For edge (s,d): out[d] += r[s]*e_k ; out[s] += r[d]*e_k.
//
// Evidence: r8 flat (499->496) despite halving CSR traffic/LDS work => CSR
// phases were not traffic-bound. Remaining suspects: 9-dispatch chain with
// latency-serial scans (scanB = 1 thread x 123 dependent loads ~35us;
// scanA/scanC/m2b ~8-10us each). This round deletes the scan trio + m2b:
//   hist1 : 123 blocks x 8192-entry chunks; u8 node histogram in LDS.
//   m2a   : per-group partial prefix (u8) + gsum, fused r->fp16.
//   m2c   : per-node deg from 8 gsum reads -> gbase; seg[n]={start,end} via
//           wave-scan + lane63 atomicAdd(cursor, wave_total) (781 atomics).
//   fill3 : chunk replay; pos = seg[c].x + gbase + base + LDS cursor++.
//   gather: split-wave, 2 entries/wave, float4 e rows (nt), fp16 r.
// 6 dispatches total (+4B memset).

#define D_FEAT 128
#define SCAN_TILE 1024
#define CHUNK 8192
#define G_GRP 8

typedef float vf4 __attribute__((ext_vector_type(4)));
typedef unsigned long long ull_t;

// ---------- fp16 pack/unpack ----------
__device__ inline unsigned pack_h2(float a, float b) {
    __half2 h;
    h.x = __float2half_rn(a);
    h.y = __float2half_rn(b);
    return *reinterpret_cast<unsigned*>(&h);
}
__device__ inline float2 unpack_h2(unsigned u) {
    __half2 h = *reinterpret_cast<__half2*>(&u);
    return __half22float2(h);
}

// ---------- hist1: per-chunk LDS u8 histogram ----------
__global__ __launch_bounds__(256) void hist1_kernel(
    const int* __restrict__ a, unsigned* __restrict__ ghist,
    int n_entries, int nwords) {
    extern __shared__ unsigned h[];
    for (int i = threadIdx.x; i < nwords; i += blockDim.x) h[i] = 0u;
    __syncthreads();
    int s = blockIdx.x * CHUNK;
    int e = s + CHUNK;
    if (e > n_entries) e = n_entries;
    for (int idx = s + threadIdx.x; idx < e; idx += blockDim.x) {
        int n = a[idx];
        atomicAdd(&h[n >> 2], 1u << ((n & 3) * 8));
    }
    __syncthreads();
    unsigned* dst = ghist + (size_t)blockIdx.x * nwords;
    for (int i = threadIdx.x; i < nwords; i += blockDim.x) dst[i] = h[i];
}

// ---------- m2a: per-group partial prefix + fused r->fp16 ----------
__global__ void m2a_kernel(const unsigned* __restrict__ ghist,
                           const float* __restrict__ r,
                           unsigned char* __restrict__ base,
                           unsigned char* __restrict__ gsum,
                           uint2* __restrict__ r16,
                           int n_nodes, int nblk, int gblk, int nwords,
                           int n_r4) {
    int n = blockIdx.x * blockDim.x + threadIdx.x;
    if (n < n_nodes) {
        int g = blockIdx.y;
        int b0 = g * gblk;
        int b1 = b0 + gblk;
        if (b1 > nblk) b1 = nblk;
        int w = n >> 2, sh = (n & 3) * 8;
        int run = 0;
        for (int b = b0; b < b1; ++b) {
            base[(size_t)b * n_nodes + n] = (unsigned char)run;
            run += (int)((ghist[(size_t)b * nwords + w] >> sh) & 0xffu);
        }
        gsum[(size_t)blockIdx.y * n_nodes + n] = (unsigned char)run;
    }
    // fused r -> fp16 (streaming, spread over full 2D grid)
    int tid = (blockIdx.y * gridDim.x + blockIdx.x) * blockDim.x + threadIdx.x;
    int nth = gridDim.x * gridDim.y * blockDim.x;
    for (int i = tid; i < n_r4; i += nth) {
        const float4 v = ((const float4*)r)[i];
        uint2 p;
        p.x = pack_h2(v.x, v.y);
        p.y = pack_h2(v.z, v.w);
        r16[i] = p;
    }
}

// ---------- m2c: deg + gbase + wave-aggregated segment allocation ----------
__global__ void m2c_kernel(const unsigned char* __restrict__ gsum,
                           unsigned char* __restrict__ gbase,
                           int2* __restrict__ seg, int* __restrict__ cursor,
                           int n_nodes) {
    int n = blockIdx.x * blockDim.x + threadIdx.x;
    int lane = threadIdx.x & 63;
    int run = 0;
    if (n < n_nodes) {
        #pragma unroll
        for (int g = 0; g < G_GRP; ++g) {
            gbase[(size_t)g * n_nodes + n] = (unsigned char)run;
            run += (int)gsum[(size_t)g * n_nodes + n];
        }
    }
    // wave-inclusive scan of run (all 64 lanes participate)
    int x = run;
    #pragma unroll
    for (int off = 1; off < 64; off <<= 1) {
        int y = __shfl_up(x, off, 64);
        if (lane >= off) x += y;
    }
    int wbase = 0;
    if (lane == 63) wbase = atomicAdd(cursor, x);   // x@63 = wave total
    wbase = __shfl(wbase, 63, 64);
    if (n < n_nodes) {
        int start = wbase + (x - run);
        seg[n] = make_int2(start, start + run);
    }
}

// ---------- fill3: chunk replay, LDS cursor, u8 base + u8 gbase ----------
__global__ __launch_bounds__(256) void fill3_kernel(
    const int* __restrict__ a, const int2* __restrict__ seg,
    const unsigned char* __restrict__ base,
    const unsigned char* __restrict__ gbase, int2* __restrict__ pl,
    int n_entries, int n_nodes, int nwords, int gblk) {
    extern __shared__ unsigned cur[];
    for (int i = threadIdx.x; i < nwords; i += blockDim.x) cur[i] = 0u;
    __syncthreads();
    int s = blockIdx.x * CHUNK;
    int e = s + CHUNK;
    if (e > n_entries) e = n_entries;
    const unsigned char* brow = base + (size_t)blockIdx.x * n_nodes;
    const unsigned char* grow = gbase + (size_t)(blockIdx.x / gblk) * n_nodes;
    for (int idx = s + threadIdx.x; idx < e; idx += blockDim.x) {
        int other  = a[idx];
        int center = a[idx ^ 1];
        int sh = (center & 3) * 8;
        unsigned old = atomicAdd(&cur[center >> 2], 1u << sh);
        int local = (int)((old >> sh) & 0xffu);
        int pos = seg[center].x + (int)grow[center] + (int)brow[center] + local;
        pl[pos] = make_int2(idx >> 1, other);
    }
}

// ---------- gather: split-wave, 2 entries/wave, float4 rows ----------
__global__ __launch_bounds__(256) void gather_w2_kernel(
    const unsigned* __restrict__ r16, const float* __restrict__ e,
    const int2* __restrict__ seg, const int2* __restrict__ pl,
    float* __restrict__ out, int n_nodes) {
    int n = blockIdx.x * 4 + (threadIdx.x >> 6);
    if (n >= n_nodes) return;
    int lane = threadIdx.x & 63;
    int half = lane >> 5;            // which entry of the pair
    int l32  = lane & 31;            // feats 4*l32 .. 4*l32+3
    int2 sg = seg[n];
    int start = sg.x;
    int end = sg.y;
    float ax = 0.f, ay = 0.f, az = 0.f, aw = 0.f;
    int i = start;
    #define PAIR_STEP(OFS)                                                    \
        {                                                                     \
            ull_t w = __builtin_nontemporal_load(                             \
                (const ull_t*)(pl + i + (OFS) + half));                       \
            int ei = (int)(unsigned)w;                                        \
            int oi = (int)(w >> 32);                                          \
            vf4 ev = __builtin_nontemporal_load(                              \
                ((const vf4*)(e + (size_t)ei * D_FEAT)) + l32);               \
            uint2 ru = *(((const uint2*)(r16 + (size_t)oi * 64)) + l32);      \
            float2 rlo = unpack_h2(ru.x);                                     \
            float2 rhi = unpack_h2(ru.y);                                     \
            ax += ev.x * rlo.x; ay += ev.y * rlo.y;                           \
            az += ev.z * rhi.x; aw += ev.w * rhi.y;                           \
        }
    for (; i + 8 <= end; i += 8) {
        PAIR_STEP(0)
        PAIR_STEP(2)
        PAIR_STEP(4)
        PAIR_STEP(6)
    }
    for (; i + 2 <= end; i += 2) {
        PAIR_STEP(0)
    }
    if (i < end && half == 0) {   // single leftover entry: half 0 only
        ull_t w = __builtin_nontemporal_load((const ull_t*)(pl + i));
        int ei = (int)(unsigned)w;
        int oi = (int)(w >> 32);
        vf4 ev = __builtin_nontemporal_load(
            ((const vf4*)(e + (size_t)ei * D_FEAT)) + l32);
        uint2 ru = *(((const uint2*)(r16 + (size_t)oi * 64)) + l32);
        float2 rlo = unpack_h2(ru.x);
        float2 rhi = unpack_h2(ru.y);
        ax += ev.x * rlo.x; ay += ev.y * rlo.y;
        az += ev.z * rhi.x; aw += ev.w * rhi.y;
    }
    #undef PAIR_STEP
    // combine the two half-wave partials (all 64 lanes active here)
    ax += __shfl_xor(ax, 32);
    ay += __shfl_xor(ay, 32);
    az += __shfl_xor(az, 32);
    aw += __shfl_xor(aw, 32);
    if (half == 0) {
        vf4 res;
        res.x = ax; res.y = ay; res.z = az; res.w = aw;
        __builtin_nontemporal_store(
            res, ((vf4*)(out + (size_t)n * D_FEAT)) + l32);
    }
}

// ================= fallback kernels =================

__global__ void hist_kernel(const int* __restrict__ a, int* __restrict__ deg,
                            int n_elems) {
    int i = blockIdx.x * blockDim.x + threadIdx.x;
    if (i < n_elems) atomicAdd(&deg[a[i]], 1);
}

__global__ void fill_kernel(const int* __restrict__ a, int* __restrict__ cursor,
                            int2* __restrict__ pl, int n_entries) {
    int k = blockIdx.x * blockDim.x + threadIdx.x;
    if (k >= n_entries) return;
    int edge = k >> 1, j = k & 1;
    int other  = a[2 * edge + j];
    int center = a[2 * edge + (j ^ 1)];
    int pos = atomicAdd(&cursor[center], 1);
    pl[pos] = make_int2(edge, other);
}

__global__ void scanA_kernel(const int* __restrict__ deg, int* __restrict__ bsum,
                             int n) {
    __shared__ int wsum[16];
    int t = threadIdx.x, lane = t & 63, w = t >> 6;
    int i = blockIdx.x * SCAN_TILE + t;
    int v = (i < n) ? deg[i] : 0;
    #pragma unroll
    for (int off = 32; off > 0; off >>= 1) v += __shfl_down(v, off, 64);
    if (lane == 0) wsum[w] = v;
    __syncthreads();
    if (t == 0) {
        int s = 0;
        #pragma unroll
        for (int k = 0; k < 16; ++k) s += wsum[k];
        bsum[blockIdx.x] = s;
    }
}

__global__ void scanB_kernel(int* __restrict__ bsum, int* __restrict__ bbase,
                             int* __restrict__ offs, int nblk, int n) {
    if (threadIdx.x == 0) {
        int run = 0;
        for (int b = 0; b < nblk; ++b) {
            bbase[b] = run;
            run += bsum[b];
        }
        offs[n] = run;
    }
}

__global__ void scanC_cursor_kernel(int* __restrict__ deg, int* __restrict__ offs,
                                    const int* __restrict__ bbase, int n) {
    __shared__ int wsum[16];
    int t = threadIdx.x, lane = t & 63, w = t >> 6;
    int i = blockIdx.x * SCAN_TILE + t;
    int v = (i < n) ? deg[i] : 0;
    int x = v;
    #pragma unroll
    for (int off = 1; off < 64; off <<= 1) {
        int y = __shfl_up(x, off, 64);
        if (lane >= off) x += y;
    }
    if (lane == 63) wsum[w] = x;
    __syncthreads();
    if (w == 0 && lane < 16) {
        int s = wsum[lane];
        #pragma unroll
        for (int off = 1; off < 16; off <<= 1) {
            int y = __shfl_up(s, off, 64);
            if (lane >= off) s += y;
        }
        wsum[lane] = s;
    }
    __syncthreads();
    int wbase = (w == 0) ? 0 : wsum[w - 1];
    if (i < n) {
        int excl = x - v + wbase + bbase[blockIdx.x];
        offs[i] = excl;
        deg[i] = excl;   // cursor for fill
    }
}

__global__ __launch_bounds__(256) void gather_f32_kernel(
    const float* __restrict__ r, const float* __restrict__ e,
    const int* __restrict__ offs, const int2* __restrict__ pl,
    float* __restrict__ out, int n_nodes) {
    int n = blockIdx.x * 4 + (threadIdx.x >> 6);
    if (n >= n_nodes) return;
    int lane = threadIdx.x & 63;
    int start = offs[n];
    int end = offs[n + 1];
    float accx = 0.f, accy = 0.f;
    for (int i = start; i < end; ++i) {
        int2 p0 = pl[i];
        float2 ev0 = *((const float2*)(e + (size_t)p0.x * D_FEAT) + lane);
        float2 rv0 = *((const float2*)(r + (size_t)p0.y * D_FEAT) + lane);
        accx += ev0.x * rv0.x;
        accy += ev0.y * rv0.y;
    }
    float2 res;
    res.x = accx;
    res.y = accy;
    *((float2*)(out + (size_t)n * D_FEAT) + lane) = res;
}

__global__ void mp_scatter_kernel(const float* __restrict__ r,
                                  const float* __restrict__ e,
                                  const int* __restrict__ a,
                                  float* __restrict__ out,
                                  int n_edges) {
    long long gid = (long long)blockIdx.x * blockDim.x + threadIdx.x;
    int edge = (int)(gid >> 7);
    int feat = (int)(gid & 127);
    if (edge >= n_edges) return;
    int s = a[2 * edge];
    int d = a[2 * edge + 1];
    float ev = e[(long long)edge * D_FEAT + feat];
    float rs = r[(long long)s * D_FEAT + feat];
    float rd = r[(long long)d * D_FEAT + feat];
    atomicAdd(&out[(long long)d * D_FEAT + feat], rs * ev);
    atomicAdd(&out[(long long)s * D_FEAT + feat], rd * ev);
}

extern "C" void kernel_launch(void* const* d_in, const int* in_sizes, int n_in,
                              void* d_out, int out_size, void* d_ws, size_t ws_size,
                              hipStream_t stream) {
    const float* r = (const float*)d_in[0];
    const float* e = (const float*)d_in[1];
    const int*   a = (const int*)d_in[2];
    float* out = (float*)d_out;
    (void)n_in;

    int n_nodes   = in_sizes[0] / D_FEAT;
    int n_edges   = in_sizes[1] / D_FEAT;
    int n_entries = 2 * n_edges;
    int n_r4      = in_sizes[0] / 4;

    int block = 256;
    int grid_e = (n_entries + block - 1) / block;
    int nblk_scan = (n_nodes + SCAN_TILE - 1) / SCAN_TILE;
    int nblk_c = (n_entries + CHUNK - 1) / CHUNK;   // chunk blocks
    int gblk   = (nblk_c + G_GRP - 1) / G_GRP;      // chunks per merge group
    int nwords = (n_nodes + 3) / 4;                 // u8 counters packed in u32
    size_t lds_bytes = (size_t)nwords * sizeof(unsigned);

    // ---- main path ws layout:
    //   ghist[nblk_c*nwords u32] | base[nblk_c*N u8] | gsum[G*N u8] |
    //   gbase[G*N u8] | r16[n_r4 uint2] | seg[N int2] | cursor[int] | pad |
    //   pl[2E int2]
    {
        size_t ghist_words = (size_t)nblk_c * nwords;
        size_t base_bytes  = (((size_t)nblk_c * n_nodes) + 7) & ~(size_t)7;
        size_t gsum_bytes  = (((size_t)G_GRP * n_nodes) + 7) & ~(size_t)7;
        size_t head_bytes  = ghist_words * 4 + base_bytes + 2 * gsum_bytes
                           + (size_t)n_r4 * sizeof(uint2)
                           + (size_t)n_nodes * sizeof(int2)
                           + 8;   // cursor + pad
        head_bytes = (head_bytes + 7) & ~(size_t)7;
        size_t need = head_bytes + (size_t)n_entries * sizeof(int2);
        if (ws_size >= need && lds_bytes <= 64 * 1024) {
            unsigned*      ghist = (unsigned*)d_ws;
            unsigned char* basep = (unsigned char*)(ghist + ghist_words);
            unsigned char* gsum  = basep + base_bytes;
            unsigned char* gbase = gsum + gsum_bytes;
            uint2*         r16   = (uint2*)(gbase + gsum_bytes);
            int2*          seg   = (int2*)(r16 + n_r4);
            int*           cursor= (int*)(seg + n_nodes);
            int2*          pl    = (int2*)((char*)d_ws + head_bytes);

            hipMemsetAsync(cursor, 0, sizeof(int), stream);
            hist1_kernel<<<nblk_c, block, lds_bytes, stream>>>(a, ghist,
                                                               n_entries,
                                                               nwords);
            dim3 gm2a((n_nodes + block - 1) / block, G_GRP);
            m2a_kernel<<<gm2a, block, 0, stream>>>(ghist, r, basep, gsum, r16,
                                                   n_nodes, nblk_c, gblk,
                                                   nwords, n_r4);
            int grid_m = (n_nodes + block - 1) / block;
            m2c_kernel<<<grid_m, block, 0, stream>>>(gsum, gbase, seg, cursor,
                                                     n_nodes);
            fill3_kernel<<<nblk_c, block, lds_bytes, stream>>>(
                a, seg, basep, gbase, pl, n_entries, n_nodes, nwords, gblk);
            int grid_g = (n_nodes + 3) / 4;
            gather_w2_kernel<<<grid_g, 256, 0, stream>>>(
                (const unsigned*)r16, e, seg, pl, out, n_nodes);
            return;
        }
    }

    // ---- fallback 1: global-atomic CSR + fp32 gather
    {
        size_t ints_head = (size_t)n_nodes + (size_t)(n_nodes + 1)
                         + 2 * (size_t)nblk_scan;
        ints_head = (ints_head + 1) & ~(size_t)1;
        size_t need = ints_head * sizeof(int) + (size_t)n_entries * sizeof(int2);
        if (ws_size >= need && nblk_scan <= 1024) {
            int*  deg  = (int*)d_ws;
            int*  offs = deg + n_nodes;
            int*  bsum = offs + n_nodes + 1;
            int*  bbase= bsum + nblk_scan;
            int2* pl   = (int2*)((int*)d_ws + ints_head);

            hipMemsetAsync(deg, 0, (size_t)n_nodes * sizeof(int), stream);
            hist_kernel<<<grid_e, block, 0, stream>>>(a, deg, n_entries);
            scanA_kernel<<<nblk_scan, SCAN_TILE, 0, stream>>>(deg, bsum, n_nodes);
            scanB_kernel<<<1, 64, 0, stream>>>(bsum, bbase, offs, nblk_scan,
                                               n_nodes);
            scanC_cursor_kernel<<<nblk_scan, SCAN_TILE, 0, stream>>>(deg, offs,
                                                                     bbase,
                                                                     n_nodes);
            fill_kernel<<<grid_e, block, 0, stream>>>(a, deg, pl, n_entries);
            int grid_g = (n_nodes + 3) / 4;
            gather_f32_kernel<<<grid_g, 256, 0, stream>>>(r, e, offs, pl, out,
                                                          n_nodes);
            return;
        }
    }

    // ---- fallback 2: atomic scatter
    hipMemsetAsync(d_out, 0, (size_t)out_size * sizeof(float), stream);
    long long total = (long long)n_edges * D_FEAT;
    long long grid = (total + block - 1) / block;
    mp_scatter_kernel<<<(int)grid, block, 0, stream>>>(r, e, a, out, n_edges);
}